// Round 10
// baseline (181.444 us; speedup 1.0000x reference)
//
#include <hip/hip_runtime.h>

// ALSTM: adaptive-computation-time LSTM.
//  - sum(w)==1  =>  output = (w@H)@W_out^T + b_out ; only hbar/cbar needed.
//  - steps after halting have w==0 and cannot affect n => early exit exact
//    (b_halt=1 => p0~0.73, halts at t=1: only 2 of 101 steps run).
// R9 post-mortem: register-pinning W_hh is allocator-defeated (3 rounds,
// VGPR stuck ~104). R10: W_hh lives in LDS as bf16 -- 32 rows x 2048 =
// 128 KB fits gfx950's 160 KB LDS. Staged once in the prologue; recurrence
// steps do ZERO global weight traffic. h packed bf16 to match (error
// ~1e-3 << 4.5e-2 threshold). Mailbox sync unchanged (R6).

#define HID    2048
#define INS    1024
#define OUTS   1024
#define MSTEPS 100
#define NBLK   256
#define NTHR   512
#define NWAVE  8
#define JPB    8      // hidden units owned per block (256*8 = 2048)
#define RPB    32     // gate rows per block (4 gates * JPB)
#define SLOTF  16     // floats per sync slot (64 B)

typedef unsigned long long u64;
typedef unsigned int u32;

__device__ __forceinline__ float wave_reduce(float v) {
    #pragma unroll
    for (int off = 32; off > 0; off >>= 1)
        v += __shfl_down(v, off, 64);
    return v;  // lane 0 holds the sum
}

__device__ __forceinline__ u32 bf16_2(float a, float b) {   // RNE pack
    u32 ua = __float_as_uint(a), ub = __float_as_uint(b);
    ua = (ua + 0x7fffu + ((ua >> 16) & 1u)) >> 16;
    ub = (ub + 0x7fffu + ((ub >> 16) & 1u)) >> 16;
    return ua | (ub << 16);
}
__device__ __forceinline__ float blo(u32 u) { return __uint_as_float(u << 16); }
__device__ __forceinline__ float bhi(u32 u) { return __uint_as_float(u & 0xffff0000u); }

__device__ __forceinline__ u64 pack_tag(unsigned tag, float v) {
    return ((u64)tag << 32) | (u64)__float_as_uint(v);
}
__device__ __forceinline__ u64 aload(const u64* p) {
    return __hip_atomic_load(p, __ATOMIC_RELAXED, __HIP_MEMORY_SCOPE_AGENT);
}
__device__ __forceinline__ void astore(u64* p, u64 v) {
    __hip_atomic_store(p, v, __ATOMIC_RELAXED, __HIP_MEMORY_SCOPE_AGENT);
}

// ws layout (floats): [0..4096) arrive slots (256 x 64B) | [4096..8192)
// mailboxes | [8192..10240) hbuf0 | [10240..12288) hbuf1 | [12288..14336)
// hbar_g.  kernel_launch zeroes the first 32768 bytes each call.

__global__ __launch_bounds__(NTHR) void alstm_kernel(
    const float* __restrict__ x,      const float* __restrict__ h0,
    const float* __restrict__ c0,     const float* __restrict__ W_ih,
    const float* __restrict__ b_ih,   const float* __restrict__ W_hh,
    const float* __restrict__ b_hh,   const float* __restrict__ w_halt,
    const float* __restrict__ b_halt, const float* __restrict__ W_out,
    const float* __restrict__ b_out,  float* __restrict__ out,
    float* __restrict__ ws)
{
    const int b    = blockIdx.x;
    const int tid  = threadIdx.x;
    const int wave = tid >> 6;
    const int lane = tid & 63;

    float* arrive = ws;                 // 256 x SLOTF floats
    float* mail   = ws + NBLK * SLOTF;
    float* hbuf0  = ws + 2 * NBLK * SLOTF;
    float* hbuf1  = hbuf0 + HID;
    float* hbar_g = hbuf0 + 2 * HID;

    __shared__ u32   whh_u[RPB * 1024];   // 128 KB: 32 rows x 2048 bf16
    __shared__ u32   hpk[HID / 2];        // 4 KB: h as packed bf16
    __shared__ float x_lds[INS];          // 4 KB
    __shared__ float hbar_lds[HID];       // 8 KB (epilogue)
    __shared__ float gate_lds[RPB];
    __shared__ float ihx_lds[RPB];
    __shared__ float wflag_lds[RPB];
    __shared__ float red_lds[4];
    __shared__ float bcast_lds;
    __shared__ float psum[NWAVE];

    const float bh = b_halt[0];
    const int j_own = b * JPB + tid;      // valid when tid < JPB

    // Rows for this wave: lr0 .. lr0+3 ; lr = gate*8 + unit
    const int lr0   = 4 * wave;
    const int rbase = (lr0 >> 3) * HID + b * JPB + (lr0 & 7);

    #define SYNC_ROUND(tag_, part_, dot_) do {                                 \
        if (tid == 0) {                                                        \
            __threadfence();   /* wb: h stores reach coherence point */        \
            astore((u64*)(arrive + SLOTF * b), pack_tag((tag_), (part_)));     \
        }                                                                      \
        if (b == 0) {                                                          \
            float pf = 0.f;                                                    \
            if (tid < NBLK) {                                                  \
                u64 v;                                                         \
                do { v = aload((u64*)(arrive + SLOTF * tid)); }                \
                while ((unsigned)(v >> 32) != (unsigned)(tag_));               \
                pf = __uint_as_float((unsigned)v);                             \
            }                                                                  \
            float s = wave_reduce(pf);                                         \
            if (lane == 0 && wave < 4) red_lds[wave] = s;                      \
            __syncthreads();                                                   \
            if (tid == 0)                                                      \
                bcast_lds = red_lds[0] + red_lds[1] + red_lds[2] + red_lds[3]; \
            __syncthreads();                                                   \
            if (tid < NBLK)                                                    \
                astore((u64*)(mail + SLOTF * tid), pack_tag((tag_), bcast_lds)); \
        }                                                                      \
        if (tid == 0) {                                                        \
            u64 v;                                                             \
            do { v = aload((u64*)(mail + SLOTF * b)); }                        \
            while ((unsigned)(v >> 32) != (unsigned)(tag_));                   \
            bcast_lds = __uint_as_float((unsigned)v);                          \
            __threadfence();   /* inv: later plain reads see fresh data */     \
        }                                                                      \
        __syncthreads();                                                       \
        (dot_) = bcast_lds;                                                    \
    } while (0)

    // ------------- prologue: stage x, h0(bf16), W_hh(bf16->LDS) -------------
    ((float2*)x_lds)[tid] = ((const float2*)x)[tid];
    {
        float4 v = ((const float4*)h0)[tid];
        hpk[2 * tid]     = bf16_2(v.x, v.y);
        hpk[2 * tid + 1] = bf16_2(v.z, v.w);
    }
    // W_hh slice: each wave converts its own 4 rows (read & written by the
    // same wave only -> no extra sync needed for whh_u).
    #pragma unroll
    for (int rr = 0; rr < 4; ++rr) {
        const float4* src = (const float4*)(W_hh + (size_t)(rbase + rr) * HID);
        u32* dst = whh_u + (lr0 + rr) * (HID / 2);
        #pragma unroll
        for (int m = 0; m < 8; ++m) {
            float4 v = src[lane + 64 * m];
            dst[2 * (lane + 64 * m)]     = bf16_2(v.x, v.y);
            dst[2 * (lane + 64 * m) + 1] = bf16_2(v.z, v.w);
        }
    }
    __syncthreads();   // x_lds + hpk ready

    // ih_x = W_ih[:,1:]@x + b_ih + b_hh  (4 rows/wave, fp32)
    #pragma unroll
    for (int rr = 0; rr < 4; ++rr) {
        const int lr = lr0 + rr;
        const int r  = (lr >> 3) * HID + b * JPB + (lr & 7);
        const float* wrow = W_ih + (size_t)r * (INS + 1) + 1;  // 1024 payload
        const int mis = (r + 1) & 3;
        const int p0  = (4 - mis) & 3;
        const int nv  = (INS - p0) >> 2;
        const float4* wv = (const float4*)(wrow + p0);
        float acc = 0.f;
        for (int i = lane; i < nv; i += 64) {
            float4 w4 = wv[i];
            int k = p0 + 4 * i;
            acc += w4.x * x_lds[k] + w4.y * x_lds[k + 1]
                 + w4.z * x_lds[k + 2] + w4.w * x_lds[k + 3];
        }
        if (lane == 0) {
            for (int k = 0; k < p0; ++k)            acc += wrow[k] * x_lds[k];
            for (int k = p0 + 4 * nv; k < INS; ++k) acc += wrow[k] * x_lds[k];
        }
        acc = wave_reduce(acc);
        if (lane == 0) {   // read back by this wave's lane 0 only
            ihx_lds[lr]   = acc + b_ih[r] + b_hh[r];
            wflag_lds[lr] = W_ih[(size_t)r * (INS + 1)];
        }
    }

    float c_reg = 0.f, h_reg = 0.f, hbar = 0.f, cbar = 0.f;
    if (tid < JPB) c_reg = c0[j_own];

    // ------------- recurrence: W_hh and h both bf16 in LDS -------------
    float csum = 0.f, r_halt = 0.f;
    int   n_halt = 0;
    for (int t = 0; t <= MSTEPS; ++t) {
        {
            const uint4* hp = (const uint4*)hpk;
            float a0 = 0.f, a1 = 0.f, a2 = 0.f, a3 = 0.f;
            #pragma unroll
            for (int m = 0; m < 4; ++m) {
                uint4 hu = hp[lane + 64 * m];
                float h0a = blo(hu.x), h1a = bhi(hu.x);
                float h2a = blo(hu.y), h3a = bhi(hu.y);
                float h4a = blo(hu.z), h5a = bhi(hu.z);
                float h6a = blo(hu.w), h7a = bhi(hu.w);
                #pragma unroll
                for (int rr = 0; rr < 4; ++rr) {
                    const uint4* wp = (const uint4*)(whh_u + (lr0 + rr) * (HID / 2));
                    uint4 wu = wp[lane + 64 * m];
                    float s = blo(wu.x) * h0a + bhi(wu.x) * h1a
                            + blo(wu.y) * h2a + bhi(wu.y) * h3a
                            + blo(wu.z) * h4a + bhi(wu.z) * h5a
                            + blo(wu.w) * h6a + bhi(wu.w) * h7a;
                    if      (rr == 0) a0 += s;
                    else if (rr == 1) a1 += s;
                    else if (rr == 2) a2 += s;
                    else              a3 += s;
                }
            }
            a0 = wave_reduce(a0);
            a1 = wave_reduce(a1);
            a2 = wave_reduce(a2);
            a3 = wave_reduce(a3);
            if (lane == 0) {
                float bb0 = ihx_lds[lr0 + 0], bb1 = ihx_lds[lr0 + 1];
                float bb2 = ihx_lds[lr0 + 2], bb3 = ihx_lds[lr0 + 3];
                if (t == 0) {
                    bb0 += wflag_lds[lr0 + 0]; bb1 += wflag_lds[lr0 + 1];
                    bb2 += wflag_lds[lr0 + 2]; bb3 += wflag_lds[lr0 + 3];
                }
                gate_lds[lr0 + 0] = bb0 + a0;
                gate_lds[lr0 + 1] = bb1 + a1;
                gate_lds[lr0 + 2] = bb2 + a2;
                gate_lds[lr0 + 3] = bb3 + a3;
            }
        }
        __syncthreads();

        float part = 0.f;
        float* hdst = (t & 1) ? hbuf1 : hbuf0;
        if (tid < JPB) {
            float iv = gate_lds[0 * JPB + tid];
            float fv = gate_lds[1 * JPB + tid];
            float gv = gate_lds[2 * JPB + tid];
            float ov = gate_lds[3 * JPB + tid];
            iv = 1.f / (1.f + expf(-iv));
            fv = 1.f / (1.f + expf(-fv));
            gv = tanhf(gv);
            ov = 1.f / (1.f + expf(-ov));
            c_reg = fv * c_reg + iv * gv;
            h_reg = ov * tanhf(c_reg);
            hdst[j_own] = h_reg;
            part = h_reg * w_halt[j_own];
        }
        part += __shfl_down(part, 4, 64);
        part += __shfl_down(part, 2, 64);
        part += __shfl_down(part, 1, 64);

        float dotv;
        SYNC_ROUND(t + 1, part, dotv);

        float p = 1.f / (1.f + expf(-(dotv + bh)));
        float prev = csum;
        csum += p;
        bool halt_now = (csum >= 1.f - 0.01f) || (t == MSTEPS);
        float wt = halt_now ? (1.f - prev) : p;
        if (tid < JPB) { hbar += wt * h_reg; cbar += wt * c_reg; }
        if (halt_now) { n_halt = t; r_halt = 1.f - prev; break; }  // uniform

        // stage h_{t+1} as packed bf16
        {
            float4 v = ((const float4*)hdst)[tid];
            hpk[2 * tid]     = bf16_2(v.x, v.y);
            hpk[2 * tid + 1] = bf16_2(v.z, v.w);
        }
        __syncthreads();
    }

    // ------------- epilogue -------------
    if (tid < JPB) {
        out[OUTS + j_own]       = hbar;   // h_out
        out[OUTS + HID + j_own] = cbar;   // c_out
        hbar_g[j_own] = hbar;
    }
    if (b == 0 && tid == 0) out[OUTS + 2 * HID] = (float)(n_halt + 1) + r_halt;

    float dummy;
    SYNC_ROUND(n_halt + 2, 0.f, dummy);
    (void)dummy;

    __syncthreads();
    ((float4*)hbar_lds)[tid] = ((const float4*)hbar_g)[tid];
    __syncthreads();

    // output = W_out @ hbar + b_out : 4 rows/block, half-row per wave, fp32
    {
        const int row  = b * 4 + (wave & 3);
        const int half = wave >> 2;
        const float4* wrow = (const float4*)(W_out + (size_t)row * HID) + half * 256;
        const float4* hv   = (const float4*)hbar_lds + half * 256;
        float acc = 0.f;
        #pragma unroll
        for (int m = 0; m < 4; ++m) {
            float4 w4 = wrow[lane + 64 * m];
            float4 h4 = hv[lane + 64 * m];
            acc += w4.x * h4.x + w4.y * h4.y + w4.z * h4.z + w4.w * h4.w;
        }
        acc = wave_reduce(acc);
        if (lane == 0) psum[wave] = acc;
    }
    __syncthreads();
    if (tid < 4) {
        int row = b * 4 + tid;
        out[row] = psum[tid] + psum[tid + 4] + b_out[row];
    }
    #undef SYNC_ROUND
}

extern "C" void kernel_launch(void* const* d_in, const int* in_sizes, int n_in,
                              void* d_out, int out_size, void* d_ws, size_t ws_size,
                              hipStream_t stream) {
    const float* x      = (const float*)d_in[0];
    const float* h0     = (const float*)d_in[1];
    const float* c0     = (const float*)d_in[2];
    const float* W_ih   = (const float*)d_in[3];
    const float* b_ih   = (const float*)d_in[4];
    const float* W_hh   = (const float*)d_in[5];
    const float* b_hh   = (const float*)d_in[6];
    const float* w_halt = (const float*)d_in[7];
    const float* b_halt = (const float*)d_in[8];
    const float* W_out  = (const float*)d_in[9];
    const float* b_out  = (const float*)d_in[10];
    float* out = (float*)d_out;
    float* ws  = (float*)d_ws;

    // Zero arrive slots + mailboxes (ws is poisoned 0xAA by the harness).
    hipMemsetAsync(d_ws, 0, 32768, stream);

    alstm_kernel<<<dim3(NBLK), dim3(NTHR), 0, stream>>>(
        x, h0, c0, W_ih, b_ih, W_hh, b_hh, w_halt, b_halt, W_out, b_out,
        out, ws);
}

// Round 11
// 175.144 us; speedup vs baseline: 1.0360x; 1.0360x over previous
//
#include <hip/hip_runtime.h>

// ALSTM: adaptive-computation-time LSTM.
//  - sum(w)==1  =>  output = (w@H)@W_out^T + b_out ; only hbar/cbar needed.
//  - steps after halting have w==0 and cannot affect n => early exit exact
//    (b_halt=1 => p0~0.73, halts at t=1: only 2 of 101 steps run).
// R10 post-mortem: dur identical across streamed/register/LDS W_hh homes =>
// cost is ISSUE SHAPE of the one-shot streams (~1-8 loads in flight/wave;
// W_ih inner loop had runtime bound -> not unrolled -> serial round trips).
// R11: deep-MLP everywhere -- 32-load batched W_hh staging with
// sched_barrier(0) between loads and converts; W_ih matvec fully unrolled
// with 4 rows interleaved (16 loads in flight); lane-parallel peel/bias.

#define HID    2048
#define INS    1024
#define OUTS   1024
#define MSTEPS 100
#define NBLK   256
#define NTHR   512
#define NWAVE  8
#define JPB    8      // hidden units owned per block (256*8 = 2048)
#define RPB    32     // gate rows per block (4 gates * JPB)
#define SLOTF  16     // floats per sync slot (64 B)

typedef unsigned long long u64;
typedef unsigned int u32;

__device__ __forceinline__ float wave_allreduce(float v) {
    #pragma unroll
    for (int off = 32; off > 0; off >>= 1)
        v += __shfl_xor(v, off, 64);
    return v;  // all lanes hold the sum
}

__device__ __forceinline__ u32 bf16_2(float a, float b) {   // RNE pack
    u32 ua = __float_as_uint(a), ub = __float_as_uint(b);
    ua = (ua + 0x7fffu + ((ua >> 16) & 1u)) >> 16;
    ub = (ub + 0x7fffu + ((ub >> 16) & 1u)) >> 16;
    return ua | (ub << 16);
}
__device__ __forceinline__ float blo(u32 u) { return __uint_as_float(u << 16); }
__device__ __forceinline__ float bhi(u32 u) { return __uint_as_float(u & 0xffff0000u); }

__device__ __forceinline__ u64 pack_tag(unsigned tag, float v) {
    return ((u64)tag << 32) | (u64)__float_as_uint(v);
}
__device__ __forceinline__ u64 aload(const u64* p) {
    return __hip_atomic_load(p, __ATOMIC_RELAXED, __HIP_MEMORY_SCOPE_AGENT);
}
__device__ __forceinline__ void astore(u64* p, u64 v) {
    __hip_atomic_store(p, v, __ATOMIC_RELAXED, __HIP_MEMORY_SCOPE_AGENT);
}

// ws layout (floats): [0..4096) arrive slots (256 x 64B) | [4096..8192)
// mailboxes | [8192..10240) hbuf0 | [10240..12288) hbuf1 | [12288..14336)
// hbar_g.  kernel_launch zeroes the first 32768 bytes each call.

__global__ __launch_bounds__(NTHR, 2) void alstm_kernel(
    const float* __restrict__ x,      const float* __restrict__ h0,
    const float* __restrict__ c0,     const float* __restrict__ W_ih,
    const float* __restrict__ b_ih,   const float* __restrict__ W_hh,
    const float* __restrict__ b_hh,   const float* __restrict__ w_halt,
    const float* __restrict__ b_halt, const float* __restrict__ W_out,
    const float* __restrict__ b_out,  float* __restrict__ out,
    float* __restrict__ ws)
{
    const int b    = blockIdx.x;
    const int tid  = threadIdx.x;
    const int wave = tid >> 6;
    const int lane = tid & 63;

    float* arrive = ws;                 // 256 x SLOTF floats
    float* mail   = ws + NBLK * SLOTF;
    float* hbuf0  = ws + 2 * NBLK * SLOTF;
    float* hbuf1  = hbuf0 + HID;
    float* hbar_g = hbuf0 + 2 * HID;

    __shared__ u32   whh_u[RPB * 1024];   // 128 KB: 32 rows x 2048 bf16
    __shared__ u32   hpk[HID / 2];        // 4 KB: h as packed bf16
    __shared__ float x_lds[INS];          // 4 KB
    __shared__ float hbar_lds[HID];       // 8 KB (epilogue)
    __shared__ float gate_lds[RPB];
    __shared__ float ihx_lds[RPB];
    __shared__ float wflag_lds[RPB];
    __shared__ float red_lds[4];
    __shared__ float bcast_lds;
    __shared__ float psum[NWAVE];

    const float bh = b_halt[0];
    const int j_own = b * JPB + tid;      // valid when tid < JPB

    // Rows for this wave: lr0 .. lr0+3 ; lr = gate*8 + unit
    const int lr0   = 4 * wave;
    const int rbase = (lr0 >> 3) * HID + b * JPB + (lr0 & 7);

    #define SYNC_ROUND(tag_, part_, dot_) do {                                 \
        if (tid == 0) {                                                        \
            __threadfence();   /* wb: h stores reach coherence point */        \
            astore((u64*)(arrive + SLOTF * b), pack_tag((tag_), (part_)));     \
        }                                                                      \
        if (b == 0) {                                                          \
            float pf = 0.f;                                                    \
            if (tid < NBLK) {                                                  \
                u64 v;                                                         \
                do { v = aload((u64*)(arrive + SLOTF * tid)); }                \
                while ((unsigned)(v >> 32) != (unsigned)(tag_));               \
                pf = __uint_as_float((unsigned)v);                             \
            }                                                                  \
            float s = wave_allreduce(pf);                                      \
            if (lane == 0 && wave < 4) red_lds[wave] = s;                      \
            __syncthreads();                                                   \
            if (tid == 0)                                                      \
                bcast_lds = red_lds[0] + red_lds[1] + red_lds[2] + red_lds[3]; \
            __syncthreads();                                                   \
            if (tid < NBLK)                                                    \
                astore((u64*)(mail + SLOTF * tid), pack_tag((tag_), bcast_lds)); \
        }                                                                      \
        if (tid == 0) {                                                        \
            u64 v;                                                             \
            do { v = aload((u64*)(mail + SLOTF * b)); }                        \
            while ((unsigned)(v >> 32) != (unsigned)(tag_));                   \
            bcast_lds = __uint_as_float((unsigned)v);                          \
            __threadfence();   /* inv: later plain reads see fresh data */     \
        }                                                                      \
        __syncthreads();                                                       \
        (dot_) = bcast_lds;                                                    \
    } while (0)

    // ------------- prologue: stage x + h0(bf16) -------------
    ((float2*)x_lds)[tid] = ((const float2*)x)[tid];
    {
        float4 v = ((const float4*)h0)[tid];
        hpk[2 * tid]     = bf16_2(v.x, v.y);
        hpk[2 * tid + 1] = bf16_2(v.z, v.w);
    }
    __syncthreads();   // x_lds + hpk ready (before any deep load batches)

    // ---- W_hh staging: 32 batched loads, THEN converts (sched_barrier) ----
    {
        float4 st[4][8];
        #pragma unroll
        for (int rr = 0; rr < 4; ++rr) {
            const float4* src = (const float4*)(W_hh + (size_t)(rbase + rr) * HID);
            #pragma unroll
            for (int m = 0; m < 8; ++m) st[rr][m] = src[lane + 64 * m];
        }
        __builtin_amdgcn_sched_barrier(0);   // keep all 32 loads in flight
        #pragma unroll
        for (int rr = 0; rr < 4; ++rr) {
            u32* dst = whh_u + (lr0 + rr) * (HID / 2);
            #pragma unroll
            for (int m = 0; m < 8; ++m) {
                dst[2 * (lane + 64 * m)]     = bf16_2(st[rr][m].x, st[rr][m].y);
                dst[2 * (lane + 64 * m) + 1] = bf16_2(st[rr][m].z, st[rr][m].w);
            }
        }
    }

    // ---- ih_x = W_ih[:,1:]@x + b_ih + b_hh : 4 rows interleaved, unrolled ----
    float a0 = 0.f, a1 = 0.f, a2 = 0.f, a3 = 0.f;
    {
        const float*  wr_[4];
        const float4* wv_[4];
        int p0_[4];
        #pragma unroll
        for (int rr = 0; rr < 4; ++rr) {
            const int lr = lr0 + rr;
            const int r  = (lr >> 3) * HID + b * JPB + (lr & 7);
            wr_[rr] = W_ih + (size_t)r * (INS + 1) + 1;   // payload
            p0_[rr] = (4 - ((r + 1) & 3)) & 3;
            wv_[rr] = (const float4*)(wr_[rr] + p0_[rr]);
        }
        // bias/flag prefetch on lanes 0..3 (parallel, off lane-0 hot path)
        float bsum = 0.f, wflg = 0.f;
        if (lane < 4) {
            const int lr = lr0 + lane;
            const int r  = (lr >> 3) * HID + b * JPB + (lr & 7);
            bsum = b_ih[r] + b_hh[r];
            wflg = W_ih[(size_t)r * (INS + 1)];
        }
        #pragma unroll
        for (int ii = 0; ii < 4; ++ii) {
            const int i = lane + 64 * ii;
            if (i < 255) {
                #pragma unroll
                for (int rr = 0; rr < 4; ++rr) {
                    float4 w4 = wv_[rr][i];
                    const int k = p0_[rr] + 4 * i;
                    float s = w4.x * x_lds[k]     + w4.y * x_lds[k + 1]
                            + w4.z * x_lds[k + 2] + w4.w * x_lds[k + 3];
                    if      (rr == 0) a0 += s;
                    else if (rr == 1) a1 += s;
                    else if (rr == 2) a2 += s;
                    else              a3 += s;
                }
            }
        }
        // leftover 4 elements per row: lanes 0..3, one element each
        if (lane < 4) {
            #pragma unroll
            for (int rr = 0; rr < 4; ++rr) {
                const int p0 = p0_[rr];
                const int e  = (lane < p0) ? lane : 1020 + lane;
                float s = wr_[rr][e] * x_lds[e];
                if      (rr == 0) a0 += s;
                else if (rr == 1) a1 += s;
                else if (rr == 2) a2 += s;
                else              a3 += s;
            }
        }
        a0 = wave_allreduce(a0);
        a1 = wave_allreduce(a1);
        a2 = wave_allreduce(a2);
        a3 = wave_allreduce(a3);
        if (lane < 4) {
            float myacc = (lane == 0) ? a0 : (lane == 1) ? a1 : (lane == 2) ? a2 : a3;
            ihx_lds[lr0 + lane]   = myacc + bsum;
            wflag_lds[lr0 + lane] = wflg;
        }
    }

    float c_reg = 0.f, h_reg = 0.f, hbar = 0.f, cbar = 0.f;
    if (tid < JPB) c_reg = c0[j_own];

    // ------------- recurrence: W_hh and h both bf16 in LDS -------------
    float csum = 0.f, r_halt = 0.f;
    int   n_halt = 0;
    for (int t = 0; t <= MSTEPS; ++t) {
        {
            const uint4* hp = (const uint4*)hpk;
            float g0 = 0.f, g1 = 0.f, g2 = 0.f, g3 = 0.f;
            #pragma unroll
            for (int m = 0; m < 4; ++m) {
                uint4 hu = hp[lane + 64 * m];
                float h0a = blo(hu.x), h1a = bhi(hu.x);
                float h2a = blo(hu.y), h3a = bhi(hu.y);
                float h4a = blo(hu.z), h5a = bhi(hu.z);
                float h6a = blo(hu.w), h7a = bhi(hu.w);
                #pragma unroll
                for (int rr = 0; rr < 4; ++rr) {
                    const uint4* wp = (const uint4*)(whh_u + (lr0 + rr) * (HID / 2));
                    uint4 wu = wp[lane + 64 * m];
                    float s = blo(wu.x) * h0a + bhi(wu.x) * h1a
                            + blo(wu.y) * h2a + bhi(wu.y) * h3a
                            + blo(wu.z) * h4a + bhi(wu.z) * h5a
                            + blo(wu.w) * h6a + bhi(wu.w) * h7a;
                    if      (rr == 0) g0 += s;
                    else if (rr == 1) g1 += s;
                    else if (rr == 2) g2 += s;
                    else              g3 += s;
                }
            }
            g0 = wave_allreduce(g0);
            g1 = wave_allreduce(g1);
            g2 = wave_allreduce(g2);
            g3 = wave_allreduce(g3);
            if (lane < 4) {
                float myacc = (lane == 0) ? g0 : (lane == 1) ? g1 : (lane == 2) ? g2 : g3;
                float bb = ihx_lds[lr0 + lane];
                if (t == 0) bb += wflag_lds[lr0 + lane];
                gate_lds[lr0 + lane] = bb + myacc;
            }
        }
        __syncthreads();

        float part = 0.f;
        float* hdst = (t & 1) ? hbuf1 : hbuf0;
        if (tid < JPB) {
            float iv = gate_lds[0 * JPB + tid];
            float fv = gate_lds[1 * JPB + tid];
            float gv = gate_lds[2 * JPB + tid];
            float ov = gate_lds[3 * JPB + tid];
            iv = 1.f / (1.f + expf(-iv));
            fv = 1.f / (1.f + expf(-fv));
            gv = tanhf(gv);
            ov = 1.f / (1.f + expf(-ov));
            c_reg = fv * c_reg + iv * gv;
            h_reg = ov * tanhf(c_reg);
            hdst[j_own] = h_reg;
            part = h_reg * w_halt[j_own];
        }
        part += __shfl_down(part, 4, 64);
        part += __shfl_down(part, 2, 64);
        part += __shfl_down(part, 1, 64);

        float dotv;
        SYNC_ROUND(t + 1, part, dotv);

        float p = 1.f / (1.f + expf(-(dotv + bh)));
        float prev = csum;
        csum += p;
        bool halt_now = (csum >= 1.f - 0.01f) || (t == MSTEPS);
        float wt = halt_now ? (1.f - prev) : p;
        if (tid < JPB) { hbar += wt * h_reg; cbar += wt * c_reg; }
        if (halt_now) { n_halt = t; r_halt = 1.f - prev; break; }  // uniform

        // stage h_{t+1} as packed bf16
        {
            float4 v = ((const float4*)hdst)[tid];
            hpk[2 * tid]     = bf16_2(v.x, v.y);
            hpk[2 * tid + 1] = bf16_2(v.z, v.w);
        }
        __syncthreads();
    }

    // ------------- epilogue -------------
    if (tid < JPB) {
        out[OUTS + j_own]       = hbar;   // h_out
        out[OUTS + HID + j_own] = cbar;   // c_out
        hbar_g[j_own] = hbar;
    }
    if (b == 0 && tid == 0) out[OUTS + 2 * HID] = (float)(n_halt + 1) + r_halt;

    float dummy;
    SYNC_ROUND(n_halt + 2, 0.f, dummy);
    (void)dummy;

    __syncthreads();
    ((float4*)hbar_lds)[tid] = ((const float4*)hbar_g)[tid];
    __syncthreads();

    // output = W_out @ hbar + b_out : 4 rows/block, half-row per wave, fp32
    {
        const int row  = b * 4 + (wave & 3);
        const int half = wave >> 2;
        const float4* wrow = (const float4*)(W_out + (size_t)row * HID) + half * 256;
        const float4* hv   = (const float4*)hbar_lds + half * 256;
        float acc = 0.f;
        #pragma unroll
        for (int m = 0; m < 4; ++m) {
            float4 w4 = wrow[lane + 64 * m];
            float4 h4 = hv[lane + 64 * m];
            acc += w4.x * h4.x + w4.y * h4.y + w4.z * h4.z + w4.w * h4.w;
        }
        acc = wave_allreduce(acc);
        if (lane == 0) psum[wave] = acc;
    }
    __syncthreads();
    if (tid < 4) {
        int row = b * 4 + tid;
        out[row] = psum[tid] + psum[tid + 4] + b_out[row];
    }
    #undef SYNC_ROUND
}

extern "C" void kernel_launch(void* const* d_in, const int* in_sizes, int n_in,
                              void* d_out, int out_size, void* d_ws, size_t ws_size,
                              hipStream_t stream) {
    const float* x      = (const float*)d_in[0];
    const float* h0     = (const float*)d_in[1];
    const float* c0     = (const float*)d_in[2];
    const float* W_ih   = (const float*)d_in[3];
    const float* b_ih   = (const float*)d_in[4];
    const float* W_hh   = (const float*)d_in[5];
    const float* b_hh   = (const float*)d_in[6];
    const float* w_halt = (const float*)d_in[7];
    const float* b_halt = (const float*)d_in[8];
    const float* W_out  = (const float*)d_in[9];
    const float* b_out  = (const float*)d_in[10];
    float* out = (float*)d_out;
    float* ws  = (float*)d_ws;

    // Zero arrive slots + mailboxes (ws is poisoned 0xAA by the harness).
    hipMemsetAsync(d_ws, 0, 32768, stream);

    alstm_kernel<<<dim3(NBLK), dim3(NTHR), 0, stream>>>(
        x, h0, c0, W_ih, b_ih, W_hh, b_hh, w_halt, b_halt, W_out, b_out,
        out, ws);
}